// Round 1
// 356.021 us; speedup vs baseline: 1.1901x; 1.1901x over previous
//
#include <hip/hip_runtime.h>
#include <hip/hip_bf16.h>
#include <math.h>

#define D_MODEL 1024
#define DD (1024 * 1024)

typedef unsigned short ushort_t;
using short8 = __attribute__((ext_vector_type(8))) short;   // 8 bf16 (4 VGPRs)
using f32x4  = __attribute__((ext_vector_type(4))) float;   // 4 fp32 acc

#define ACT_NONE 0
#define ACT_SILU 1

__device__ __forceinline__ float bf2f(ushort_t u) {
    return __uint_as_float(((unsigned int)u) << 16);
}
__device__ __forceinline__ ushort_t f2bf(float f) {
    unsigned int x = __float_as_uint(f);
    x += 0x7fffu + ((x >> 16) & 1u);   // round-to-nearest-even
    return (ushort_t)(x >> 16);
}

#define GL2LDS(gp, lp)                                                         \
    __builtin_amdgcn_global_load_lds(                                          \
        (const __attribute__((address_space(1))) void*)(gp),                   \
        (__attribute__((address_space(3))) void*)(lp), 16, 0, 0)

// ---------------------------------------------------------------------------
// 256x256-tile, 8-phase pipelined bf16 GEMM (plain-HIP port of the m201-class
// schedule).  512 threads = 8 waves (2M x 4N), per-wave output 128x64.
// K split into NU=32 units of BK=32; ring of 4 LDS unit-buffers (A 16KB +
// B 16KB each = 128 KiB total).  Per phase: {ds_read frags | stage one 16KB
// chunk via global_load_lds | barrier | lgkmcnt(0) | setprio(1) 16xMFMA
// setprio(0) | barrier}.  Counted vmcnt(4) once per K-tile (2 units); stage
// lead = 3 units, so the wait only needs to drain past the 2 newest chunks.
// LDS k-chunk XOR swizzle (quad ^ ((lr>>1)&3)) applied on BOTH the
// pre-swizzled global source of global_load_lds and the ds_read address.
// A: M x 1024 bf16 row-major.  Bt: 1024 x 1024 bf16 N-major (Bt[n][k]).
// ---------------------------------------------------------------------------
template <int ACT, int OUTF32, int BIASF>
__global__ __launch_bounds__(512, 2) void gemm256(
    const ushort_t* __restrict__ A,
    const ushort_t* __restrict__ Bt,
    const float* __restrict__ bias,
    void* __restrict__ Cv, int M)
{
    constexpr int K = 1024, N = 1024;
    constexpr int NU = K / 32;                 // 32 K-units
    __shared__ ushort_t lds[4 * 16384];        // 128 KiB: 4 x (A 8192 + B 8192)

    const int tid  = threadIdx.x;
    const int lane = tid & 63;
    const int wave = tid >> 6;                 // 0..7
    const int quad = lane >> 4;
    const int lr   = lane & 15;
    const int wm   = wave >> 2;                // 0..1  (M-wave)
    const int wn   = wave & 3;                 // 0..3  (N-wave)
    const int bm   = blockIdx.x;
    const int bn   = blockIdx.y;

    const ushort_t* Ab = A  + (size_t)bm * 256 * K;
    const ushort_t* Bb = Bt + (size_t)bn * 256 * K;

    // staging: thread t writes LDS bytes [t*16, t*16+16) (+8192 for round 1)
    // = row (t>>2) (+128), chunk (t&3).  Inverse-swizzled global k-quad:
    const int sg    = (tid & 3) ^ ((tid >> 3) & 3);
    const size_t s0 = (size_t)(tid >> 2) * K + (size_t)sg * 8;
    const size_t s1 = s0 + (size_t)128 * K;
    const int d0 = tid * 8;                    // ushort offset in chunk region
    const int d1 = tid * 8 + 4096;

    // ds_read lane offsets (ushorts); chunk-XOR is lane-constant across mt/nt
    const int chk  = quad ^ ((lr >> 1) & 3);
    const int aoff = (wm * 128 + lr) * 32 + chk * 8;
    const int boff = (wn * 64  + lr) * 32 + chk * 8;

    f32x4 acc[8][4];
#pragma unroll
    for (int i = 0; i < 8; i++)
#pragma unroll
        for (int j = 0; j < 4; j++) acc[i][j] = (f32x4){0.f, 0.f, 0.f, 0.f};

#define SA256(su) do { const int b_ = ((su) & 3) * 16384;                      \
        GL2LDS(Ab + s0 + (su) * 32, lds + b_ + d0);                            \
        GL2LDS(Ab + s1 + (su) * 32, lds + b_ + d1); } while (0)
#define SB256(su) do { const int b_ = ((su) & 3) * 16384 + 8192;               \
        GL2LDS(Bb + s0 + (su) * 32, lds + b_ + d0);                           \
        GL2LDS(Bb + s1 + (su) * 32, lds + b_ + d1); } while (0)

    // prologue: stage units 0,1,2 (12 loads); need units 0,1 landed.
    SA256(0); SB256(0);
    SA256(1); SB256(1);
    SA256(2); SB256(2);
    asm volatile("s_waitcnt vmcnt(4)" ::: "memory");
    __builtin_amdgcn_s_barrier();

    short8 afr[4], bfr[4];
#pragma unroll
    for (int u = 0; u < NU; u += 2) {
        {   // ================= unit u =================
            const ushort_t* Ax = lds + (u & 3) * 16384;
            const ushort_t* Bx = Ax + 8192;
            // ---- phase 0: mt 0..3 ----
#pragma unroll
            for (int t = 0; t < 4; t++)
                bfr[t] = *(const short8*)(Bx + boff + t * 512);
#pragma unroll
            for (int t = 0; t < 4; t++)
                afr[t] = *(const short8*)(Ax + aoff + t * 512);
            if (u + 3 < NU) SA256(u + 3);
            __builtin_amdgcn_s_barrier();
            asm volatile("s_waitcnt lgkmcnt(0)" ::: "memory");
            __builtin_amdgcn_sched_barrier(0);
            __builtin_amdgcn_s_setprio(1);
#pragma unroll
            for (int mt = 0; mt < 4; mt++)
#pragma unroll
                for (int nt = 0; nt < 4; nt++)
                    acc[mt][nt] = __builtin_amdgcn_mfma_f32_16x16x32_bf16(
                        afr[mt], bfr[nt], acc[mt][nt], 0, 0, 0);
            __builtin_amdgcn_s_setprio(0);
            __builtin_amdgcn_s_barrier();
            // ---- phase 1: mt 4..7 (bfr reused from regs) ----
#pragma unroll
            for (int t = 0; t < 4; t++)
                afr[t] = *(const short8*)(Ax + aoff + (4 + t) * 512);
            if (u + 3 < NU) SB256(u + 3);
            __builtin_amdgcn_s_barrier();
            asm volatile("s_waitcnt lgkmcnt(0)" ::: "memory");
            __builtin_amdgcn_sched_barrier(0);
            __builtin_amdgcn_s_setprio(1);
#pragma unroll
            for (int mt = 0; mt < 4; mt++)
#pragma unroll
                for (int nt = 0; nt < 4; nt++)
                    acc[mt + 4][nt] = __builtin_amdgcn_mfma_f32_16x16x32_bf16(
                        afr[mt], bfr[nt], acc[mt + 4][nt], 0, 0, 0);
            __builtin_amdgcn_s_setprio(0);
            __builtin_amdgcn_s_barrier();
        }
        {   // ================= unit u+1 =================
            const ushort_t* Ax = lds + ((u + 1) & 3) * 16384;
            const ushort_t* Bx = Ax + 8192;
            // ---- phase 2: mt 0..3 ----
#pragma unroll
            for (int t = 0; t < 4; t++)
                bfr[t] = *(const short8*)(Bx + boff + t * 512);
#pragma unroll
            for (int t = 0; t < 4; t++)
                afr[t] = *(const short8*)(Ax + aoff + t * 512);
            if (u + 4 < NU) SA256(u + 4);
            __builtin_amdgcn_s_barrier();
            asm volatile("s_waitcnt lgkmcnt(0)" ::: "memory");
            __builtin_amdgcn_sched_barrier(0);
            __builtin_amdgcn_s_setprio(1);
#pragma unroll
            for (int mt = 0; mt < 4; mt++)
#pragma unroll
                for (int nt = 0; nt < 4; nt++)
                    acc[mt][nt] = __builtin_amdgcn_mfma_f32_16x16x32_bf16(
                        afr[mt], bfr[nt], acc[mt][nt], 0, 0, 0);
            __builtin_amdgcn_s_setprio(0);
            __builtin_amdgcn_s_barrier();
            // ---- phase 3: mt 4..7; end-of-group counted wait ----
#pragma unroll
            for (int t = 0; t < 4; t++)
                afr[t] = *(const short8*)(Ax + aoff + (4 + t) * 512);
            if (u + 4 < NU) SB256(u + 4);
            __builtin_amdgcn_s_barrier();
            asm volatile("s_waitcnt lgkmcnt(0)" ::: "memory");
            __builtin_amdgcn_sched_barrier(0);
            __builtin_amdgcn_s_setprio(1);
#pragma unroll
            for (int mt = 0; mt < 4; mt++)
#pragma unroll
                for (int nt = 0; nt < 4; nt++)
                    acc[mt + 4][nt] = __builtin_amdgcn_mfma_f32_16x16x32_bf16(
                        afr[mt], bfr[nt], acc[mt + 4][nt], 0, 0, 0);
            __builtin_amdgcn_s_setprio(0);
            if (u + 4 >= NU)
                asm volatile("s_waitcnt vmcnt(0)" ::: "memory");
            else
                asm volatile("s_waitcnt vmcnt(4)" ::: "memory");
            __builtin_amdgcn_s_barrier();
        }
    }
#undef SA256
#undef SB256

    // epilogue: bias (+SiLU), direct scalar stores
    float bv[4];
#pragma unroll
    for (int nt = 0; nt < 4; nt++)
        bv[nt] = BIASF ? bias[bn * 256 + wn * 64 + nt * 16 + lr] : 0.f;

#pragma unroll
    for (int mt = 0; mt < 8; mt++) {
#pragma unroll
        for (int nt = 0; nt < 4; nt++) {
            const int col = bn * 256 + wn * 64 + nt * 16 + lr;
#pragma unroll
            for (int r = 0; r < 4; r++) {
                const int row = bm * 256 + wm * 128 + mt * 16 + quad * 4 + r;
                float v = acc[mt][nt][r] + bv[nt];
                if (ACT == ACT_SILU) v = v / (1.f + __expf(-v));
                if (OUTF32)
                    ((float*)Cv)[(size_t)row * N + col] = v;
                else
                    ((ushort_t*)Cv)[(size_t)row * N + col] = f2bf(v);
            }
        }
    }
}

// ---------------------------------------------------------------------------
// bf16 GEMM — R2 128x128 structure (kept for the small 1024^3 Wf GEMM, where
// 64 blocks beat 16, and as fallback when M % 256 != 0).
// ---------------------------------------------------------------------------
template <int ACT, int OUTF32, int BIASF>
__global__ __launch_bounds__(256) void gemm_bf16(
    const ushort_t* __restrict__ A,
    const ushort_t* __restrict__ Bt,
    const float* __restrict__ bias,
    void* __restrict__ Cv, int M)
{
    constexpr int K = 1024, N = 1024;
    __shared__ ushort_t As[128 * 32];
    __shared__ ushort_t Bs[128 * 32];

    const int tid  = threadIdx.x;
    const int lane = tid & 63;
    const int wave = tid >> 6;
    const int quad = lane >> 4;
    const int lr   = lane & 15;
    const int bm   = blockIdx.x;
    const int bn   = blockIdx.y;
    const int wm   = (wave >> 1) * 64;
    const int wn   = (wave & 1) * 64;

    f32x4 acc[4][4];
#pragma unroll
    for (int i = 0; i < 4; i++)
#pragma unroll
        for (int j = 0; j < 4; j++) acc[i][j] = (f32x4){0.f, 0.f, 0.f, 0.f};

    int ci0 = tid, ci1 = tid + 256;
    int am0 = ci0 >> 2, akc0 = (ci0 & 3) ^ ((am0 >> 1) & 3);
    int am1 = ci1 >> 2, akc1 = (ci1 & 3) ^ ((am1 >> 1) & 3);
    const ushort_t* Ab = A + (size_t)(bm * 128) * K;
    const ushort_t* Bb = Bt + (size_t)(bn * 128) * K;

    for (int k0 = 0; k0 < K; k0 += 32) {
        GL2LDS(Ab + (size_t)am0 * K + k0 + akc0 * 8, As + ci0 * 8);
        GL2LDS(Ab + (size_t)am1 * K + k0 + akc1 * 8, As + ci1 * 8);
        GL2LDS(Bb + (size_t)am0 * K + k0 + akc0 * 8, Bs + ci0 * 8);
        GL2LDS(Bb + (size_t)am1 * K + k0 + akc1 * 8, Bs + ci1 * 8);
        __syncthreads();

        short8 af[4], bfr[4];
#pragma unroll
        for (int t = 0; t < 4; t++) {
            int m = wm + t * 16 + lr;
            af[t] = *(const short8*)(As + m * 32 + ((quad ^ ((m >> 1) & 3)) * 8));
            int n = wn + t * 16 + lr;
            bfr[t] = *(const short8*)(Bs + n * 32 + ((quad ^ ((n >> 1) & 3)) * 8));
        }
#pragma unroll
        for (int mt = 0; mt < 4; mt++)
#pragma unroll
            for (int nt = 0; nt < 4; nt++)
                acc[mt][nt] = __builtin_amdgcn_mfma_f32_16x16x32_bf16(
                    af[mt], bfr[nt], acc[mt][nt], 0, 0, 0);
        __syncthreads();
    }

    float bv[4];
#pragma unroll
    for (int nt = 0; nt < 4; nt++)
        bv[nt] = BIASF ? bias[bn * 128 + wn + nt * 16 + lr] : 0.f;

#pragma unroll
    for (int mt = 0; mt < 4; mt++) {
#pragma unroll
        for (int nt = 0; nt < 4; nt++) {
            const int col = bn * 128 + wn + nt * 16 + lr;
#pragma unroll
            for (int r = 0; r < 4; r++) {
                const int row = bm * 128 + wm + mt * 16 + quad * 4 + r;
                float v = acc[mt][nt][r] + bv[nt];
                if (ACT == ACT_SILU) v = v / (1.f + __expf(-v));
                if (OUTF32)
                    ((float*)Cv)[(size_t)row * N + col] = v;
                else
                    ((ushort_t*)Cv)[(size_t)row * N + col] = f2bf(v);
            }
        }
    }
}

// ---------------------------------------------------------------------------
// In-place LayerNorm over bf16 rows of 1024, fp32 math, eps=1e-5.
// ---------------------------------------------------------------------------
__global__ __launch_bounds__(256) void layernorm_bf16(ushort_t* __restrict__ X)
{
    const int row = blockIdx.x;
    const int tid = threadIdx.x;
    ushort_t* x = X + (size_t)row * D_MODEL + tid * 4;

    uint2 u = *(uint2*)x;
    float a = bf2f(u.x & 0xffff), b = bf2f(u.x >> 16);
    float c = bf2f(u.y & 0xffff), d = bf2f(u.y >> 16);
    float s = a + b + c + d;
    float ss = a * a + b * b + c * c + d * d;

#pragma unroll
    for (int off = 32; off > 0; off >>= 1) {
        s += __shfl_down(s, off);
        ss += __shfl_down(ss, off);
    }
    __shared__ float sbuf[4], ssbuf[4];
    const int wave = tid >> 6;
    if ((tid & 63) == 0) { sbuf[wave] = s; ssbuf[wave] = ss; }
    __syncthreads();
    const float S = sbuf[0] + sbuf[1] + sbuf[2] + sbuf[3];
    const float SS = ssbuf[0] + ssbuf[1] + ssbuf[2] + ssbuf[3];
    const float mu = S * (1.f / D_MODEL);
    const float var = SS * (1.f / D_MODEL) - mu * mu;
    const float r = rsqrtf(var + 1e-5f);

    a = (a - mu) * r; b = (b - mu) * r; c = (c - mu) * r; d = (d - mu) * r;
    u.x = (unsigned)f2bf(a) | ((unsigned)f2bf(b) << 16);
    u.y = (unsigned)f2bf(c) | ((unsigned)f2bf(d) << 16);
    *(uint2*)x = u;
}

// ---------------------------------------------------------------------------
// ONE prep dispatch (flattened 1-D grid), covering:
//  blocks [0, 6144): weight prep, 6 z-slices of 1024 blocks each
//      z=0..4: transpose+convert (wq, mlp0..2, w_out) -> bf16 N-major wt+z*DD
//      z=5:    plain convert W3 -> wt+5*DD
//  blocks [6144, 6144+M*D/2048): x fp32 -> bf16 into Q (8 elems/thread)
//  blocks [last 32): bias_compose: bf[n] = b3 @ Wout + bout, split-K in block
// ---------------------------------------------------------------------------
__global__ __launch_bounds__(256) void prep_all(
    const float* __restrict__ wq, const float* __restrict__ mlp_w,
    const float* __restrict__ w_out, const float* __restrict__ x,
    const float* __restrict__ b3, const float* __restrict__ bout,
    ushort_t* __restrict__ wt, ushort_t* __restrict__ Q,
    float* __restrict__ bf, int nxblk)
{
    const int blk = blockIdx.x;
    const int tid = threadIdx.x;

    if (blk < 6144) {                    // ---- weight prep ----
        const int z = blk >> 10;
        const int t = blk & 1023;        // 32x32 tile index
        const int k0 = (t >> 5) * 32;
        const int n0 = (t & 31) * 32;
        const int r = tid >> 5;          // 0..7
        const int c = tid & 31;          // 0..31

        if (z == 5) {                    // plain convert W3
            const float* src = mlp_w + (size_t)3 * DD;
            ushort_t* dst = wt + (size_t)5 * DD;
#pragma unroll
            for (int i = 0; i < 4; i++) {
                size_t idx = (size_t)(k0 + r + 8 * i) * D_MODEL + n0 + c;
                dst[idx] = f2bf(src[idx]);
            }
            return;
        }
        const float* src = (z == 0) ? wq : (z < 4) ? (mlp_w + (size_t)(z - 1) * DD) : w_out;
        ushort_t* dst = wt + (size_t)z * DD;
        __shared__ float tile[32][33];
#pragma unroll
        for (int i = 0; i < 4; i++)
            tile[r + 8 * i][c] = src[(size_t)(k0 + r + 8 * i) * D_MODEL + n0 + c];
        __syncthreads();
#pragma unroll
        for (int i = 0; i < 4; i++)
            dst[(size_t)(n0 + r + 8 * i) * D_MODEL + k0 + c] = f2bf(tile[c][r + 8 * i]);
        return;
    }
    if (blk < 6144 + nxblk) {            // ---- x -> bf16 ----
        int i = (blk - 6144) * 256 + tid;
        const float4* p = (const float4*)(x + (size_t)i * 8);
        float4 v0 = p[0], v1 = p[1];
        union { ushort_t u[8]; uint4 v; } pk;
        pk.u[0] = f2bf(v0.x); pk.u[1] = f2bf(v0.y);
        pk.u[2] = f2bf(v0.z); pk.u[3] = f2bf(v0.w);
        pk.u[4] = f2bf(v1.x); pk.u[5] = f2bf(v1.y);
        pk.u[6] = f2bf(v1.z); pk.u[7] = f2bf(v1.w);
        *(uint4*)(Q + (size_t)i * 8) = pk.v;
        return;
    }
    // ---- bias_compose: 32 blocks, each 32 n-cols, split-K 8-way ----
    {
        const int b = blk - 6144 - nxblk;        // 0..31
        const int n = b * 32 + (tid & 31);
        const int kg = tid >> 5;                 // 0..7
        float s = 0.f;
        for (int k = kg * 128; k < (kg + 1) * 128; k++)
            s = fmaf(b3[k], w_out[(size_t)k * D_MODEL + n], s);
        __shared__ float red[8][32];
        red[kg][tid & 31] = s;
        __syncthreads();
        if (kg == 0) {
            float t = 0.f;
#pragma unroll
            for (int j = 0; j < 8; j++) t += red[j][tid & 31];
            bf[n] = t + bout[n];
        }
    }
}

// ---------------------------------------------------------------------------
extern "C" void kernel_launch(void* const* d_in, const int* in_sizes, int n_in,
                              void* d_out, int out_size, void* d_ws, size_t ws_size,
                              hipStream_t stream)
{
    const float* x     = (const float*)d_in[0];
    const float* wq    = (const float*)d_in[1];
    const float* bq    = (const float*)d_in[2];
    const float* mlp_w = (const float*)d_in[3];
    const float* mlp_b = (const float*)d_in[4];
    const float* w_out = (const float*)d_in[5];
    const float* b_out = (const float*)d_in[6];

    const int D = D_MODEL;
    const int M = in_sizes[0] / D;   // 16384

    // ws layout (ushort units):
    // wt[0..5)=transposed weights | [5DD,6DD)=W3 plain | [6DD,7DD)=WfT
    // | Q (M*D) | bf (1024 fp32)
    ushort_t* wt  = (ushort_t*)d_ws;
    ushort_t* w3b = wt + (size_t)5 * DD;
    ushort_t* wtF = wt + (size_t)6 * DD;
    ushort_t* Q   = wt + (size_t)7 * DD;
    float*    bf  = (float*)(Q + (size_t)M * D);
    ushort_t* P   = (ushort_t*)d_out;   // bf16 acts alias d_out's fp32 buffer

    // 1. all prep in one dispatch
    const int nxblk = M * D / 2048;     // x-convert blocks (8 elems/thread)
    prep_all<<<6144 + nxblk + 32, 256, 0, stream>>>(
        wq, mlp_w, w_out, x, mlp_b + 3 * D, b_out, wt, Q, bf, nxblk);
    // 2. Wf^T = Wout^T @ W3^T  (N-major rep of Wf = W3*Wout) — small GEMM,
    //    keep 128^2 kernel (64 blocks > 16 blocks of the 256^2 kernel)
    gemm_bf16<ACT_NONE, 0, 0><<<dim3(8, 8), 256, 0, stream>>>(
        wt + (size_t)4 * DD, w3b, nullptr, wtF, 1024);

    if ((M & 255) == 0) {
        dim3 grid(M / 256, D / 256);    // 64 x 4 = 256 blocks = 1/CU
        // 3. q = x @ wq + bq -> P
        gemm256<ACT_NONE, 0, 1><<<grid, 512, 0, stream>>>(Q, wt + (size_t)0 * DD, bq, P, M);
        // 4. LN in place on P
        layernorm_bf16<<<M, 256, 0, stream>>>(P);
        // 5-7. MLP layers 0..2 with SiLU
        gemm256<ACT_SILU, 0, 1><<<grid, 512, 0, stream>>>(P, wt + (size_t)1 * DD, mlp_b + 0 * D, Q, M);
        gemm256<ACT_SILU, 0, 1><<<grid, 512, 0, stream>>>(Q, wt + (size_t)2 * DD, mlp_b + 1 * D, P, M);
        gemm256<ACT_SILU, 0, 1><<<grid, 512, 0, stream>>>(P, wt + (size_t)3 * DD, mlp_b + 2 * D, Q, M);
        // 8. fused (layer3 + out proj): out = h3 @ Wf + bf -> d_out fp32
        gemm256<ACT_NONE, 1, 1><<<grid, 512, 0, stream>>>(Q, wtF, bf, d_out, M);
    } else {
        dim3 grid(M / 128, D / 128);
        gemm_bf16<ACT_NONE, 0, 1><<<grid, 256, 0, stream>>>(Q, wt + (size_t)0 * DD, bq, P, M);
        layernorm_bf16<<<M, 256, 0, stream>>>(P);
        gemm_bf16<ACT_SILU, 0, 1><<<grid, 256, 0, stream>>>(P, wt + (size_t)1 * DD, mlp_b + 0 * D, Q, M);
        gemm_bf16<ACT_SILU, 0, 1><<<grid, 256, 0, stream>>>(Q, wt + (size_t)2 * DD, mlp_b + 1 * D, P, M);
        gemm_bf16<ACT_SILU, 0, 1><<<grid, 256, 0, stream>>>(P, wt + (size_t)3 * DD, mlp_b + 2 * D, Q, M);
        gemm_bf16<ACT_NONE, 1, 1><<<grid, 256, 0, stream>>>(Q, wtF, bf, d_out, M);
    }
}

// Round 2
// 354.452 us; speedup vs baseline: 1.1954x; 1.0044x over previous
//
#include <hip/hip_runtime.h>
#include <hip/hip_bf16.h>
#include <math.h>

#define D_MODEL 1024
#define DD (1024 * 1024)

typedef unsigned short ushort_t;
using short8 = __attribute__((ext_vector_type(8))) short;   // 8 bf16 (4 VGPRs)
using f32x4  = __attribute__((ext_vector_type(4))) float;   // 4 fp32 acc

#define ACT_NONE 0
#define ACT_SILU 1

__device__ __forceinline__ float bf2f(ushort_t u) {
    return __uint_as_float(((unsigned int)u) << 16);
}
__device__ __forceinline__ ushort_t f2bf(float f) {
    unsigned int x = __float_as_uint(f);
    x += 0x7fffu + ((x >> 16) & 1u);   // round-to-nearest-even
    return (ushort_t)(x >> 16);
}

#define GL2LDS(gp, lp)                                                         \
    __builtin_amdgcn_global_load_lds(                                          \
        (const __attribute__((address_space(1))) void*)(gp),                   \
        (__attribute__((address_space(3))) void*)(lp), 16, 0, 0)

// ---------------------------------------------------------------------------
// 256x256-tile bf16 GEMM with one-phase-ahead register prefetch and counted
// lgkm waits (HK derived-waits style).  512 threads = 8 waves (2M x 4N),
// per-wave output 128x64.  K = 32 units of BK=32; ring of 4 LDS unit-buffers.
//
// Per unit u (2 phases, ONE barrier each):
//   even(2u):  issue afrO[u] | vmcnt(4) | bar | stage SA(u+3) | lgkm(4)
//              (drains afrE[u]+bfr[u], leaves afrO) | 16 MFMA (afrE,bfr)
//   odd(2u+1): issue afrE[u+1] | vmcnt(4) | bar | stage SB(u+3) | lgkm(4)
//              (drains afrO[u], leaves afrE) | 16 MFMA (afrO,bfr)
//              | issue bfr[u+1]  (late; streams under next bar+stage)
//
// Hazard proofs (counted-wait discipline):
//  WAR slot-reuse: SA/SB(u+3) writes slot (u-1)&3, issued AFTER phase 2u's
//    barrier; program order puts every wave's phase-(2u-1) lgkm(4) (which
//    drains all unit-(u-1) reads) before that barrier.  Safe.
//  RAW stage->read: vmcnt(4) per phase drains loads issued 3 phases back, so
//    unit u (staged phases 2u-6/2u-5) is drained at phase 2u-2 and published
//    by its barrier, before the first unit-u read issue at phase 2u-1 top.
//  Register WAR: every prefetch writes regs last read by the MFMA cluster
//    immediately preceding it (compiler-visible dependence); the single
//    unordered ds_read pair (late bfr -> next RAO) is pinned by
//    sched_barrier(0).
// ---------------------------------------------------------------------------
template <int ACT, int OUTF32, int BIASF>
__global__ __launch_bounds__(512, 2) void gemm256(
    const ushort_t* __restrict__ A,
    const ushort_t* __restrict__ Bt,
    const float* __restrict__ bias,
    void* __restrict__ Cv, int M)
{
    constexpr int K = 1024, N = 1024;
    constexpr int NU = K / 32;                 // 32 K-units
    __shared__ ushort_t lds[4 * 16384];        // 128 KiB: 4 x (A 8192 + B 8192)

    const int tid  = threadIdx.x;
    const int lane = tid & 63;
    const int wave = tid >> 6;                 // 0..7
    const int quad = lane >> 4;
    const int lr   = lane & 15;
    const int wm   = wave >> 2;                // 0..1  (M-wave)
    const int wn   = wave & 3;                 // 0..3  (N-wave)
    const int bm   = blockIdx.x;
    const int bn   = blockIdx.y;

    const ushort_t* Ab = A  + (size_t)bm * 256 * K;
    const ushort_t* Bb = Bt + (size_t)bn * 256 * K;

    // staging: thread t writes LDS bytes [t*16, t*16+16) (+8192 for row+128)
    const int sg    = (tid & 3) ^ ((tid >> 3) & 3);   // inverse k-chunk swizzle
    const size_t s0 = (size_t)(tid >> 2) * K + (size_t)sg * 8;
    const size_t s1 = s0 + (size_t)128 * K;
    const int d0 = tid * 8;
    const int d1 = tid * 8 + 4096;

    // ds_read lane offsets (ushorts); chunk-XOR matches the staged swizzle
    const int chk  = quad ^ ((lr >> 1) & 3);
    const int aoff = (wm * 128 + lr) * 32 + chk * 8;
    const int boff = (wn * 64  + lr) * 32 + chk * 8;

    short8 bfr[4], afrE[4], afrO[4];
    f32x4 acc[8][4];
#pragma unroll
    for (int i = 0; i < 8; i++)
#pragma unroll
        for (int j = 0; j < 4; j++) acc[i][j] = (f32x4){0.f, 0.f, 0.f, 0.f};

#define SA(v) do { const int b_ = ((v) & 3) * 16384;                           \
        GL2LDS(Ab + s0 + (v) * 32, lds + b_ + d0);                             \
        GL2LDS(Ab + s1 + (v) * 32, lds + b_ + d1); } while (0)
#define SB(v) do { const int b_ = ((v) & 3) * 16384 + 8192;                    \
        GL2LDS(Bb + s0 + (v) * 32, lds + b_ + d0);                             \
        GL2LDS(Bb + s1 + (v) * 32, lds + b_ + d1); } while (0)
#define RAE(v) do { const ushort_t* p_ = lds + ((v) & 3) * 16384 + aoff;       \
        afrE[0] = *(const short8*)(p_);                                        \
        afrE[1] = *(const short8*)(p_ + 512);                                  \
        afrE[2] = *(const short8*)(p_ + 1024);                                 \
        afrE[3] = *(const short8*)(p_ + 1536); } while (0)
#define RAO(v) do { const ushort_t* p_ = lds + ((v) & 3) * 16384 + aoff + 2048;\
        afrO[0] = *(const short8*)(p_);                                        \
        afrO[1] = *(const short8*)(p_ + 512);                                  \
        afrO[2] = *(const short8*)(p_ + 1024);                                 \
        afrO[3] = *(const short8*)(p_ + 1536); } while (0)
#define RB(v) do { const ushort_t* p_ = lds + ((v) & 3) * 16384 + 8192 + boff; \
        bfr[0] = *(const short8*)(p_);                                         \
        bfr[1] = *(const short8*)(p_ + 512);                                   \
        bfr[2] = *(const short8*)(p_ + 1024);                                  \
        bfr[3] = *(const short8*)(p_ + 1536); } while (0)

    // prologue: stage units 0,1,2 (12 loads); drain unit 0; first frag reads.
    SA(0); SB(0);
    SA(1); SB(1);
    SA(2); SB(2);
    asm volatile("s_waitcnt vmcnt(8)" ::: "memory");
    __builtin_amdgcn_s_barrier();
    RAE(0);
    RB(0);
    __builtin_amdgcn_sched_barrier(0);   // pin issue order before loop's RAO

#pragma unroll
    for (int u = 0; u < NU; ++u) {
        // ---------------- even phase (2u) ----------------
        RAO(u);                                   // prefetch for odd phase
        asm volatile("s_waitcnt vmcnt(4)" ::: "memory");
        __builtin_amdgcn_s_barrier();
        if (u + 3 < NU) SA(u + 3);
        asm volatile("s_waitcnt lgkmcnt(4)" ::: "memory");  // afrE,bfr ready
        __builtin_amdgcn_sched_barrier(0);
        __builtin_amdgcn_s_setprio(1);
#pragma unroll
        for (int mt = 0; mt < 4; mt++)
#pragma unroll
            for (int nt = 0; nt < 4; nt++)
                acc[mt][nt] = __builtin_amdgcn_mfma_f32_16x16x32_bf16(
                    afrE[mt], bfr[nt], acc[mt][nt], 0, 0, 0);
        __builtin_amdgcn_s_setprio(0);
        // ---------------- odd phase (2u+1) ----------------
        if (u + 1 < NU) RAE(u + 1);               // prefetch for next even
        asm volatile("s_waitcnt vmcnt(4)" ::: "memory");
        __builtin_amdgcn_s_barrier();
        if (u + 3 < NU) SB(u + 3);
        if (u + 1 < NU)
            asm volatile("s_waitcnt lgkmcnt(4)" ::: "memory"); // afrO ready
        else
            asm volatile("s_waitcnt lgkmcnt(0)" ::: "memory");
        __builtin_amdgcn_sched_barrier(0);
        __builtin_amdgcn_s_setprio(1);
#pragma unroll
        for (int mt = 0; mt < 4; mt++)
#pragma unroll
            for (int nt = 0; nt < 4; nt++)
                acc[mt + 4][nt] = __builtin_amdgcn_mfma_f32_16x16x32_bf16(
                    afrO[mt], bfr[nt], acc[mt + 4][nt], 0, 0, 0);
        __builtin_amdgcn_s_setprio(0);
        if (u + 1 < NU) {
            RB(u + 1);                            // late bfr prefetch
            __builtin_amdgcn_sched_barrier(0);    // keep before next RAO
        }
    }
#undef SA
#undef SB
#undef RAE
#undef RAO
#undef RB

    // epilogue: bias (+SiLU), direct scalar stores
    float bv[4];
#pragma unroll
    for (int nt = 0; nt < 4; nt++)
        bv[nt] = BIASF ? bias[bn * 256 + wn * 64 + nt * 16 + lr] : 0.f;

#pragma unroll
    for (int mt = 0; mt < 8; mt++) {
#pragma unroll
        for (int nt = 0; nt < 4; nt++) {
            const int col = bn * 256 + wn * 64 + nt * 16 + lr;
#pragma unroll
            for (int r = 0; r < 4; r++) {
                const int row = bm * 256 + wm * 128 + mt * 16 + quad * 4 + r;
                float v = acc[mt][nt][r] + bv[nt];
                if (ACT == ACT_SILU) v = v / (1.f + __expf(-v));
                if (OUTF32)
                    ((float*)Cv)[(size_t)row * N + col] = v;
                else
                    ((ushort_t*)Cv)[(size_t)row * N + col] = f2bf(v);
            }
        }
    }
}

// ---------------------------------------------------------------------------
// bf16 GEMM — R2 128x128 structure (kept for the small 1024^3 Wf GEMM and as
// fallback when M % 256 != 0).
// ---------------------------------------------------------------------------
template <int ACT, int OUTF32, int BIASF>
__global__ __launch_bounds__(256) void gemm_bf16(
    const ushort_t* __restrict__ A,
    const ushort_t* __restrict__ Bt,
    const float* __restrict__ bias,
    void* __restrict__ Cv, int M)
{
    constexpr int K = 1024, N = 1024;
    __shared__ ushort_t As[128 * 32];
    __shared__ ushort_t Bs[128 * 32];

    const int tid  = threadIdx.x;
    const int lane = tid & 63;
    const int wave = tid >> 6;
    const int quad = lane >> 4;
    const int lr   = lane & 15;
    const int bm   = blockIdx.x;
    const int bn   = blockIdx.y;
    const int wm   = (wave >> 1) * 64;
    const int wn   = (wave & 1) * 64;

    f32x4 acc[4][4];
#pragma unroll
    for (int i = 0; i < 4; i++)
#pragma unroll
        for (int j = 0; j < 4; j++) acc[i][j] = (f32x4){0.f, 0.f, 0.f, 0.f};

    int ci0 = tid, ci1 = tid + 256;
    int am0 = ci0 >> 2, akc0 = (ci0 & 3) ^ ((am0 >> 1) & 3);
    int am1 = ci1 >> 2, akc1 = (ci1 & 3) ^ ((am1 >> 1) & 3);
    const ushort_t* Ab = A + (size_t)(bm * 128) * K;
    const ushort_t* Bb = Bt + (size_t)(bn * 128) * K;

    for (int k0 = 0; k0 < K; k0 += 32) {
        GL2LDS(Ab + (size_t)am0 * K + k0 + akc0 * 8, As + ci0 * 8);
        GL2LDS(Ab + (size_t)am1 * K + k0 + akc1 * 8, As + ci1 * 8);
        GL2LDS(Bb + (size_t)am0 * K + k0 + akc0 * 8, Bs + ci0 * 8);
        GL2LDS(Bb + (size_t)am1 * K + k0 + akc1 * 8, Bs + ci1 * 8);
        __syncthreads();

        short8 af[4], bfr[4];
#pragma unroll
        for (int t = 0; t < 4; t++) {
            int m = wm + t * 16 + lr;
            af[t] = *(const short8*)(As + m * 32 + ((quad ^ ((m >> 1) & 3)) * 8));
            int n = wn + t * 16 + lr;
            bfr[t] = *(const short8*)(Bs + n * 32 + ((quad ^ ((n >> 1) & 3)) * 8));
        }
#pragma unroll
        for (int mt = 0; mt < 4; mt++)
#pragma unroll
            for (int nt = 0; nt < 4; nt++)
                acc[mt][nt] = __builtin_amdgcn_mfma_f32_16x16x32_bf16(
                    af[mt], bfr[nt], acc[mt][nt], 0, 0, 0);
        __syncthreads();
    }

    float bv[4];
#pragma unroll
    for (int nt = 0; nt < 4; nt++)
        bv[nt] = BIASF ? bias[bn * 128 + wn + nt * 16 + lr] : 0.f;

#pragma unroll
    for (int mt = 0; mt < 4; mt++) {
#pragma unroll
        for (int nt = 0; nt < 4; nt++) {
            const int col = bn * 128 + wn + nt * 16 + lr;
#pragma unroll
            for (int r = 0; r < 4; r++) {
                const int row = bm * 128 + wm + mt * 16 + quad * 4 + r;
                float v = acc[mt][nt][r] + bv[nt];
                if (ACT == ACT_SILU) v = v / (1.f + __expf(-v));
                if (OUTF32)
                    ((float*)Cv)[(size_t)row * N + col] = v;
                else
                    ((ushort_t*)Cv)[(size_t)row * N + col] = f2bf(v);
            }
        }
    }
}

// ---------------------------------------------------------------------------
// In-place LayerNorm over bf16 rows of 1024, fp32 math, eps=1e-5.
// ---------------------------------------------------------------------------
__global__ __launch_bounds__(256) void layernorm_bf16(ushort_t* __restrict__ X)
{
    const int row = blockIdx.x;
    const int tid = threadIdx.x;
    ushort_t* x = X + (size_t)row * D_MODEL + tid * 4;

    uint2 u = *(uint2*)x;
    float a = bf2f(u.x & 0xffff), b = bf2f(u.x >> 16);
    float c = bf2f(u.y & 0xffff), d = bf2f(u.y >> 16);
    float s = a + b + c + d;
    float ss = a * a + b * b + c * c + d * d;

#pragma unroll
    for (int off = 32; off > 0; off >>= 1) {
        s += __shfl_down(s, off);
        ss += __shfl_down(ss, off);
    }
    __shared__ float sbuf[4], ssbuf[4];
    const int wave = tid >> 6;
    if ((tid & 63) == 0) { sbuf[wave] = s; ssbuf[wave] = ss; }
    __syncthreads();
    const float S = sbuf[0] + sbuf[1] + sbuf[2] + sbuf[3];
    const float SS = ssbuf[0] + ssbuf[1] + ssbuf[2] + ssbuf[3];
    const float mu = S * (1.f / D_MODEL);
    const float var = SS * (1.f / D_MODEL) - mu * mu;
    const float r = rsqrtf(var + 1e-5f);

    a = (a - mu) * r; b = (b - mu) * r; c = (c - mu) * r; d = (d - mu) * r;
    u.x = (unsigned)f2bf(a) | ((unsigned)f2bf(b) << 16);
    u.y = (unsigned)f2bf(c) | ((unsigned)f2bf(d) << 16);
    *(uint2*)x = u;
}

// ---------------------------------------------------------------------------
// ONE prep dispatch (flattened 1-D grid), covering:
//  blocks [0, 6144): weight prep, 6 z-slices of 1024 blocks each
//      z=0..4: transpose+convert (wq, mlp0..2, w_out) -> bf16 N-major wt+z*DD
//      z=5:    plain convert W3 -> wt+5*DD
//  blocks [6144, 6144+M*D/2048): x fp32 -> bf16 into Q (8 elems/thread)
//  blocks [last 32): bias_compose: bf[n] = b3 @ Wout + bout, split-K in block
// ---------------------------------------------------------------------------
__global__ __launch_bounds__(256) void prep_all(
    const float* __restrict__ wq, const float* __restrict__ mlp_w,
    const float* __restrict__ w_out, const float* __restrict__ x,
    const float* __restrict__ b3, const float* __restrict__ bout,
    ushort_t* __restrict__ wt, ushort_t* __restrict__ Q,
    float* __restrict__ bf, int nxblk)
{
    const int blk = blockIdx.x;
    const int tid = threadIdx.x;

    if (blk < 6144) {                    // ---- weight prep ----
        const int z = blk >> 10;
        const int t = blk & 1023;        // 32x32 tile index
        const int k0 = (t >> 5) * 32;
        const int n0 = (t & 31) * 32;
        const int r = tid >> 5;          // 0..7
        const int c = tid & 31;          // 0..31

        if (z == 5) {                    // plain convert W3
            const float* src = mlp_w + (size_t)3 * DD;
            ushort_t* dst = wt + (size_t)5 * DD;
#pragma unroll
            for (int i = 0; i < 4; i++) {
                size_t idx = (size_t)(k0 + r + 8 * i) * D_MODEL + n0 + c;
                dst[idx] = f2bf(src[idx]);
            }
            return;
        }
        const float* src = (z == 0) ? wq : (z < 4) ? (mlp_w + (size_t)(z - 1) * DD) : w_out;
        ushort_t* dst = wt + (size_t)z * DD;
        __shared__ float tile[32][33];
#pragma unroll
        for (int i = 0; i < 4; i++)
            tile[r + 8 * i][c] = src[(size_t)(k0 + r + 8 * i) * D_MODEL + n0 + c];
        __syncthreads();
#pragma unroll
        for (int i = 0; i < 4; i++)
            dst[(size_t)(n0 + r + 8 * i) * D_MODEL + k0 + c] = f2bf(tile[c][r + 8 * i]);
        return;
    }
    if (blk < 6144 + nxblk) {            // ---- x -> bf16 ----
        int i = (blk - 6144) * 256 + tid;
        const float4* p = (const float4*)(x + (size_t)i * 8);
        float4 v0 = p[0], v1 = p[1];
        union { ushort_t u[8]; uint4 v; } pk;
        pk.u[0] = f2bf(v0.x); pk.u[1] = f2bf(v0.y);
        pk.u[2] = f2bf(v0.z); pk.u[3] = f2bf(v0.w);
        pk.u[4] = f2bf(v1.x); pk.u[5] = f2bf(v1.y);
        pk.u[6] = f2bf(v1.z); pk.u[7] = f2bf(v1.w);
        *(uint4*)(Q + (size_t)i * 8) = pk.v;
        return;
    }
    // ---- bias_compose: 32 blocks, each 32 n-cols, split-K 8-way ----
    {
        const int b = blk - 6144 - nxblk;        // 0..31
        const int n = b * 32 + (tid & 31);
        const int kg = tid >> 5;                 // 0..7
        float s = 0.f;
        for (int k = kg * 128; k < (kg + 1) * 128; k++)
            s = fmaf(b3[k], w_out[(size_t)k * D_MODEL + n], s);
        __shared__ float red[8][32];
        red[kg][tid & 31] = s;
        __syncthreads();
        if (kg == 0) {
            float t = 0.f;
#pragma unroll
            for (int j = 0; j < 8; j++) t += red[j][tid & 31];
            bf[n] = t + bout[n];
        }
    }
}

// ---------------------------------------------------------------------------
extern "C" void kernel_launch(void* const* d_in, const int* in_sizes, int n_in,
                              void* d_out, int out_size, void* d_ws, size_t ws_size,
                              hipStream_t stream)
{
    const float* x     = (const float*)d_in[0];
    const float* wq    = (const float*)d_in[1];
    const float* bq    = (const float*)d_in[2];
    const float* mlp_w = (const float*)d_in[3];
    const float* mlp_b = (const float*)d_in[4];
    const float* w_out = (const float*)d_in[5];
    const float* b_out = (const float*)d_in[6];

    const int D = D_MODEL;
    const int M = in_sizes[0] / D;   // 16384

    // ws layout (ushort units):
    // wt[0..5)=transposed weights | [5DD,6DD)=W3 plain | [6DD,7DD)=WfT
    // | Q (M*D) | bf (1024 fp32)
    ushort_t* wt  = (ushort_t*)d_ws;
    ushort_t* w3b = wt + (size_t)5 * DD;
    ushort_t* wtF = wt + (size_t)6 * DD;
    ushort_t* Q   = wt + (size_t)7 * DD;
    float*    bf  = (float*)(Q + (size_t)M * D);
    ushort_t* P   = (ushort_t*)d_out;   // bf16 acts alias d_out's fp32 buffer

    // 1. all prep in one dispatch
    const int nxblk = M * D / 2048;     // x-convert blocks (8 elems/thread)
    prep_all<<<6144 + nxblk + 32, 256, 0, stream>>>(
        wq, mlp_w, w_out, x, mlp_b + 3 * D, b_out, wt, Q, bf, nxblk);
    // 2. Wf^T = Wout^T @ W3^T  (N-major rep of Wf = W3*Wout) — small GEMM,
    //    keep 128^2 kernel (64 blocks > 16 blocks of the 256^2 kernel)
    gemm_bf16<ACT_NONE, 0, 0><<<dim3(8, 8), 256, 0, stream>>>(
        wt + (size_t)4 * DD, w3b, nullptr, wtF, 1024);

    if ((M & 255) == 0) {
        dim3 grid(M / 256, D / 256);    // 64 x 4 = 256 blocks = 1/CU
        // 3. q = x @ wq + bq -> P
        gemm256<ACT_NONE, 0, 1><<<grid, 512, 0, stream>>>(Q, wt + (size_t)0 * DD, bq, P, M);
        // 4. LN in place on P
        layernorm_bf16<<<M, 256, 0, stream>>>(P);
        // 5-7. MLP layers 0..2 with SiLU
        gemm256<ACT_SILU, 0, 1><<<grid, 512, 0, stream>>>(P, wt + (size_t)1 * DD, mlp_b + 0 * D, Q, M);
        gemm256<ACT_SILU, 0, 1><<<grid, 512, 0, stream>>>(Q, wt + (size_t)2 * DD, mlp_b + 1 * D, P, M);
        gemm256<ACT_SILU, 0, 1><<<grid, 512, 0, stream>>>(P, wt + (size_t)3 * DD, mlp_b + 2 * D, Q, M);
        // 8. fused (layer3 + out proj): out = h3 @ Wf + bf -> d_out fp32
        gemm256<ACT_NONE, 1, 1><<<grid, 512, 0, stream>>>(Q, wtF, bf, d_out, M);
    } else {
        dim3 grid(M / 128, D / 128);
        gemm_bf16<ACT_NONE, 0, 1><<<grid, 256, 0, stream>>>(Q, wt + (size_t)0 * DD, bq, P, M);
        layernorm_bf16<<<M, 256, 0, stream>>>(P);
        gemm_bf16<ACT_SILU, 0, 1><<<grid, 256, 0, stream>>>(P, wt + (size_t)1 * DD, mlp_b + 0 * D, Q, M);
        gemm_bf16<ACT_SILU, 0, 1><<<grid, 256, 0, stream>>>(Q, wt + (size_t)2 * DD, mlp_b + 1 * D, P, M);
        gemm_bf16<ACT_SILU, 0, 1><<<grid, 256, 0, stream>>>(P, wt + (size_t)3 * DD, mlp_b + 2 * D, Q, M);
        gemm_bf16<ACT_NONE, 1, 1><<<grid, 256, 0, stream>>>(Q, wtF, bf, d_out, M);
    }
}